// Round 4
// baseline (1429.693 us; speedup 1.0000x reference)
//
#include <hip/hip_runtime.h>

typedef unsigned short u16;
typedef unsigned int   u32;
typedef short bf16x8 __attribute__((ext_vector_type(8)));
typedef short bf16x4 __attribute__((ext_vector_type(4)));
typedef float f32x4  __attribute__((ext_vector_type(4)));

#define TT   131072         // B*N tokens
#define SCALE 0.17677669529663687f

__device__ __forceinline__ float bf2f(u32 u) {
    u32 v = u << 16;
    float f;
    __builtin_memcpy(&f, &v, 4);
    return f;
}
__device__ __forceinline__ u16 f2bf(float f) {
    u32 v;
    __builtin_memcpy(&v, &f, 4);
    u32 r = v + 0x7fffu + ((v >> 16) & 1u);
    return (u16)(r >> 16);
}

// pack two f32 -> one u32 of 2 bf16 (RNE) in a single instruction
__device__ __forceinline__ u32 cvtpk(float a, float b) {
    u32 r;
    asm("v_cvt_pk_bf16_f32 %0, %1, %2" : "=v"(r) : "v"(a), "v"(b));
    return r;
}

#if __has_builtin(__builtin_amdgcn_mfma_f32_16x16x16bf16_1k)
#define HAVE_MFMA16_BUILTIN 1
#endif

__device__ __forceinline__ f32x4 mfma16(bf16x4 a, bf16x4 b, f32x4 c) {
#ifdef HAVE_MFMA16_BUILTIN
    return __builtin_amdgcn_mfma_f32_16x16x16bf16_1k(a, b, c, 0, 0, 0);
#else
    asm volatile("v_mfma_f32_16x16x16_bf16 %0, %1, %2, %0"
                 : "+v"(c) : "v"(a), "v"(b));
    return c;
#endif
}

// async global->LDS, 16B per lane, dest = uniform base + lane*16
#define GLD16(g, l)                                                           \
    __builtin_amdgcn_global_load_lds(                                         \
        (const __attribute__((address_space(1))) void*)(g),                   \
        (__attribute__((address_space(3))) void*)(l), 16, 0, 0)

// ---------------- weight fp32 -> bf16 conversion (once per launch) ----------
// wbf element layout:
//   qkvw [0,196608)  fc1w [196608,458752)  fc2w [458752,720896)
//   pjl  [720896,983040)  rows c of [projw(256) | W'(768)]  (W' by compose)
//   zero16 [983040,983048)
__global__ __launch_bounds__(256) void cvt_kernel(
    const float* __restrict__ qkvw, const float* __restrict__ projw,
    const float* __restrict__ fc1w, const float* __restrict__ fc2w,
    u16* __restrict__ dst) {
    int i = blockIdx.x * 256 + threadIdx.x;
    if (i >= 983048) return;
    float v;
    if (i < 196608)       v = qkvw[i];
    else if (i < 458752)  v = fc1w[i - 196608];
    else if (i < 720896)  v = fc2w[i - 458752];
    else if (i < 983040) {
        int local = i - 720896;
        int kk = local & 1023;
        if (kk >= 256) return;          // W' part written by compose_kernel
        v = projw[(local >> 10) * 256 + kk];
    } else v = 0.0f;                    // zero16 block
    dst[i] = f2bf(v);
}

// ---- compose W'[c, tap*256+ci] = sum_j projw[c,j]*posw[j,ci,tap] (fp32) ----
// also bias2[c] = projb[c] + sum_j projw[c,j]*posb[j]
__global__ __launch_bounds__(256) void compose_kernel(
    const float* __restrict__ projw, const float* __restrict__ posw,
    const float* __restrict__ projb, const float* __restrict__ posb,
    u16* __restrict__ pjl, float* __restrict__ bias2) {
    int c = blockIdx.x, t = threadIdx.x;
    __shared__ float pr[256];
    pr[t] = projw[c * 256 + t];
    __syncthreads();
    #pragma unroll
    for (int r = 0; r < 3; ++r) {
        int kp = r * 256 + t;
        int tap = kp >> 8, ci = kp & 255;
        float acc = 0.f;
        for (int j = 0; j < 256; ++j)
            acc += pr[j] * posw[j * 768 + ci * 3 + tap];
        pjl[(size_t)c * 1024 + 256 + kp] = f2bf(acc);
    }
    float b = pr[t] * posb[t];
    #pragma unroll
    for (int o = 32; o > 0; o >>= 1) b += __shfl_down(b, o);
    __shared__ float pb4[4];
    if ((t & 63) == 0) pb4[t >> 6] = b;
    __syncthreads();
    if (t == 0) bias2[c] = projb[c] + pb4[0] + pb4[1] + pb4[2] + pb4[3];
}

// ---------------- LayerNorm (+optional intra-batch roll), fp32 in -> bf16 out
// wave-per-token: 4 tokens/block, 64 lanes x 4ch, shuffle-only reduction.
template <int SH>
__global__ __launch_bounds__(256) void ln_kernel(const float* __restrict__ x,
                                                 const float* __restrict__ w,
                                                 const float* __restrict__ bb,
                                                 u16* __restrict__ out) {
    int wid = threadIdx.x >> 6, lane = threadIdx.x & 63;
    int tl = blockIdx.x * 4 + wid;
    int src = (tl & ~4095) | ((tl + SH) & 4095);
    int c = lane * 4;
    float4 v = *(const float4*)(x + (size_t)src * 256 + c);
    float s1 = v.x + v.y + v.z + v.w;
    float s2 = v.x * v.x + v.y * v.y + v.z * v.z + v.w * v.w;
    #pragma unroll
    for (int o = 32; o > 0; o >>= 1) {
        s1 += __shfl_xor(s1, o);
        s2 += __shfl_xor(s2, o);
    }
    float mean = s1 * (1.0f / 256.0f);
    float rs = rsqrtf(s2 * (1.0f / 256.0f) - mean * mean + 1e-5f);
    float4 wv = *(const float4*)(w + c);
    float4 bv = *(const float4*)(bb + c);
    uint2 o2;
    o2.x = cvtpk((v.x - mean) * rs * wv.x + bv.x, (v.y - mean) * rs * wv.y + bv.y);
    o2.y = cvtpk((v.z - mean) * rs * wv.z + bv.z, (v.w - mean) * rs * wv.w + bv.w);
    *(uint2*)(out + (size_t)tl * 256 + c) = o2;
}

// ---------------- MFMA GEMM: C = A[M,K]bf16 @ W[Nc,K]bf16^T + bias ----------
// 256x128 block tile, BK=32, 4 waves (2Mx2N), per-wave 128x64 (8x4 acc of
// 16x16x32 MFMA) -> 43.7 FLOP per LDS byte (vs 32 at 64x64, which exactly
// saturated the LDS pipe at MFMA peak). 2-phase double-buffered LDS with
// prefetch-before-compute, one vmcnt(0)+barrier per K-step.
// MODE 0: Cb[r*Nc+c]  = v                         (qkv / fc1)
// MODE 2: Cf[drl*256+c] = v + resf[drl*256+c]     (proj + reverse-roll + residual)
// MODE 3: Cf[r*256+c]   = v + resf[r*256+c]       (fc2 + residual -> d_out)
// ACT 1: exact GELU
// AM 1: fused proj+LePE A-operand: K=1024, row t = [attn(256) | v(t-1) | v(t) | v(t+1)]
//       attn from A, v-taps direct from qkv (A2); window-edge taps -> Z (zeros)
template <int MODE, int ACT, int AM>
__global__ __launch_bounds__(256) void mgemm(
    const u16* __restrict__ A, const u16* __restrict__ A2,
    const u16* __restrict__ W, const u16* __restrict__ Z,
    const float* __restrict__ bias, u16* __restrict__ Cb,
    float* __restrict__ Cf, const float* __restrict__ resf,
    int Nc, int K) {
    __shared__ u16 As[2][256 * 32];   // 32 KB
    __shared__ u16 Bs[2][128 * 32];   // 16 KB
    const int tid = threadIdx.x;
    const int m0 = blockIdx.x * 256, n0 = blockIdx.y * 128;
    const int w4 = tid >> 6, lane = tid & 63;
    // staging: per K-step, wave w stages A rows {w*16+l/4 + 64i, i=0..3} and
    // B rows {w*16+l/4 + 64j, j=0..1}; lane -> (row, 16B col group)
    const int arow = w4 * 16 + (lane >> 2);
    const int scol = (lane & 3) * 8;                 // element offset in row
    const u16* ag = (AM == 0) ? A + (size_t)(m0 + arow) * K + scol : A;
    const u16* bg = W + (size_t)(n0 + arow) * K + scol;
    // fragments
    const int frow = lane & 15, fk = (lane >> 4) * 8;
    const int am = (w4 & 1) * 128, bn = (w4 >> 1) * 64;

    f32x4 acc[8][4];
    #pragma unroll
    for (int i = 0; i < 8; ++i)
        #pragma unroll
        for (int j = 0; j < 4; ++j) acc[i][j] = (f32x4){0.f, 0.f, 0.f, 0.f};

    auto STAGE = [&](int b, int k0) {
        u16* lA0 = &As[b][(w4 * 16) * 32];
        u16* lB0 = &Bs[b][(w4 * 16) * 32];
        if constexpr (AM == 0) {
            #pragma unroll
            for (int i = 0; i < 4; ++i)
                GLD16(ag + (size_t)(64 * i) * K + k0, lA0 + i * 2048);
        } else {
            const int rg = k0 >> 8;                  // region (wave-uniform)
            const int kl = k0 & 255;
            if (rg == 0) {
                #pragma unroll
                for (int i = 0; i < 4; ++i)
                    GLD16(A + (size_t)(m0 + arow + 64 * i) * 256 + scol + kl,
                          lA0 + i * 2048);
            } else {
                const int dr = rg - 2;               // tap offset -1/0/+1
                #pragma unroll
                for (int i = 0; i < 4; ++i) {
                    int t = m0 + arow + 64 * i;
                    int tq = t & 63;
                    bool edge = (dr == -1) ? (tq == 0)
                              : (dr == 1)  ? (tq == 63) : false;
                    const u16* p = edge ? Z
                        : A2 + (size_t)(t + dr) * 768 + 512 + scol + kl;
                    GLD16(p, lA0 + i * 2048);
                }
            }
        }
        GLD16(bg + k0, lB0);
        GLD16(bg + (size_t)64 * K + k0, lB0 + 2048);
    };
    auto COMPUTE = [&](int b) {
        bf16x8 bfr[4];
        #pragma unroll
        for (int ni = 0; ni < 4; ++ni)
            bfr[ni] = *(const bf16x8*)&Bs[b][(bn + ni * 16 + frow) * 32 + fk];
        #pragma unroll
        for (int mi = 0; mi < 8; ++mi) {
            bf16x8 af = *(const bf16x8*)&As[b][(am + mi * 16 + frow) * 32 + fk];
            #pragma unroll
            for (int ni = 0; ni < 4; ++ni)
                acc[mi][ni] = __builtin_amdgcn_mfma_f32_16x16x32_bf16(
                    af, bfr[ni], acc[mi][ni], 0, 0, 0);
        }
    };

    // prologue
    STAGE(0, 0);
    asm volatile("s_waitcnt vmcnt(0)" ::: "memory");
    __syncthreads();
    int cur = 0;
    const int nt = K >> 5;
    for (int t = 0; t < nt - 1; ++t) {
        STAGE(cur ^ 1, (t + 1) << 5);   // prefetch next K-step (async, in flight
        COMPUTE(cur);                   //  during ds_read + MFMA of current)
        asm volatile("s_waitcnt vmcnt(0)" ::: "memory");
        __syncthreads();
        cur ^= 1;
    }
    COMPUTE(cur);                       // epilogue tile (no prefetch)

    // epilogue; C/D layout: col = lane&15, row = (lane>>4)*4 + reg
    const int erow = am + ((lane >> 4) << 2);
    const int ecol = bn + (lane & 15);
    #pragma unroll
    for (int ni = 0; ni < 4; ++ni) {
        int c = n0 + ecol + ni * 16;
        float bv = bias[c];
        #pragma unroll
        for (int mi = 0; mi < 8; ++mi) {
            #pragma unroll
            for (int reg = 0; reg < 4; ++reg) {
                int r = m0 + erow + mi * 16 + reg;
                float v = acc[mi][ni][reg] + bv;
                if (ACT == 1) v = 0.5f * v * (1.0f + erff(v * 0.70710678118654752f));
                if (MODE == 0) {
                    Cb[(size_t)r * Nc + c] = f2bf(v);
                } else if (MODE == 2) {
                    size_t drl = (size_t)((r & ~4095) | ((r + 32) & 4095));
                    Cf[drl * 256 + c] = v + resf[drl * 256 + c];
                } else {
                    Cf[(size_t)r * 256 + c] = v + resf[(size_t)r * 256 + c];
                }
            }
        }
    }
}

// ---------------- MFMA attention: one block per window, wave = 2 heads ------
// Swapped QK^T: S^T[k,q] = mfma_16x16x32(K-rows, Q-rows). Lane (g=lane>>4,
// q15=lane&15) holds S^T[16*mt+4*g+r, 16*nt+q15] — which is EXACTLY the
// B-fragment layout of v_mfma_f32_16x16x16_bf16 (lane holds B[4g+j, q15],
// j == reg). So softmax + cvt_pk happen fully in-lane, then PV computes
// out^T = V^T @ P^T with V^T staged in LDS (32x[64+pad] per head).
__global__ __launch_bounds__(256) void attn_mfma(const u16* __restrict__ qkv,
                                                 const float* __restrict__ mask,
                                                 u16* __restrict__ outb) {
    __shared__ u16 Vt[8][32][68];     // V^T per head, k-pad 68 (8B-aligned rows)
    __shared__ float Mt[64][68];      // mask^T [k][q], pad 68 -> 2-way reads
    __shared__ int mflag;

    const int w   = blockIdx.x;       // global window within chunk
    const int nw  = w & 63;           // window within batch
    const int tid = threadIdx.x;
    const int wid = tid >> 6, lane = tid & 63;
    const int g = lane >> 4, q15 = lane & 15;

    if (tid == 0) mflag = 0;
    __syncthreads();

    // ---- stage mask^T + nonzero detect (all-zero for most windows) ----
    {
        const float* mrow = mask + (size_t)nw * 4096;
        int nz = 0;
        #pragma unroll
        for (int i = 0; i < 16; ++i) {
            int e = i * 256 + tid;                  // e = q*64 + k
            float m = mrow[e];
            nz |= (m != 0.0f);
            Mt[e & 63][e >> 6] = m;
        }
        if (nz) mflag = 1;
    }

    // ---- stage V^T for all 8 heads (write banks: lanes walk t -> free) ----
    {
        const u16* vg = qkv + (size_t)(w * 64) * 768 + 512;
        #pragma unroll
        for (int p = 0; p < 8; ++p) {
            int t  = lane;                          // token within window
            int c0 = wid * 8 + p * 32;              // channel base (uniform/wave)
            uint4 u = *(const uint4*)(vg + (size_t)t * 768 + c0);
            u16 el[8];
            *(uint4*)el = u;
            int h = c0 >> 5, d0 = c0 & 31;
            #pragma unroll
            for (int j = 0; j < 8; ++j) Vt[h][d0 + j][t] = el[j];
        }
    }
    __syncthreads();

    const int hasmask = mflag;

    #pragma unroll
    for (int hh = 0; hh < 2; ++hh) {
        const int h = wid * 2 + hh;

        // ---- QK^T (swapped): A = K rows, B = Q rows, direct from global ----
        const u16* kbase = qkv + (size_t)(w * 64) * 768 + 256 + h * 32 + g * 8;
        const u16* qbase = qkv + (size_t)(w * 64) * 768 +       h * 32 + g * 8;
        bf16x8 kf[4], qf[4];
        #pragma unroll
        for (int mt = 0; mt < 4; ++mt)
            kf[mt] = *(const bf16x8*)(kbase + (size_t)(16 * mt + q15) * 768);
        #pragma unroll
        for (int nt = 0; nt < 4; ++nt)
            qf[nt] = *(const bf16x8*)(qbase + (size_t)(16 * nt + q15) * 768);

        f32x4 s[4][4];
        #pragma unroll
        for (int mt = 0; mt < 4; ++mt)
            #pragma unroll
            for (int nt = 0; nt < 4; ++nt) s[mt][nt] = (f32x4){0.f, 0.f, 0.f, 0.f};
        #pragma unroll
        for (int mt = 0; mt < 4; ++mt)
            #pragma unroll
            for (int nt = 0; nt < 4; ++nt)
                s[mt][nt] = __builtin_amdgcn_mfma_f32_16x16x32_bf16(
                    kf[mt], qf[nt], s[mt][nt], 0, 0, 0);

        // ---- scale (+mask) ----
        if (hasmask) {
            #pragma unroll
            for (int mt = 0; mt < 4; ++mt)
                #pragma unroll
                for (int nt = 0; nt < 4; ++nt)
                    #pragma unroll
                    for (int r = 0; r < 4; ++r)
                        s[mt][nt][r] = s[mt][nt][r] * SCALE +
                                       Mt[16 * mt + 4 * g + r][16 * nt + q15];
        } else {
            #pragma unroll
            for (int mt = 0; mt < 4; ++mt)
                #pragma unroll
                for (int nt = 0; nt < 4; ++nt)
                    #pragma unroll
                    for (int r = 0; r < 4; ++r)
                        s[mt][nt][r] *= SCALE;
        }

        // ---- softmax over k (rows of S^T): in-lane 16 + shfl_xor 16/32 ----
        float inv[4];
        #pragma unroll
        for (int nt = 0; nt < 4; ++nt) {
            float mx = -3.0e38f;
            #pragma unroll
            for (int mt = 0; mt < 4; ++mt)
                #pragma unroll
                for (int r = 0; r < 4; ++r) mx = fmaxf(mx, s[mt][nt][r]);
            mx = fmaxf(mx, __shfl_xor(mx, 16));
            mx = fmaxf(mx, __shfl_xor(mx, 32));
            float sum = 0.f;
            #pragma unroll
            for (int mt = 0; mt < 4; ++mt)
                #pragma unroll
                for (int r = 0; r < 4; ++r) {
                    float p = __expf(s[mt][nt][r] - mx);
                    s[mt][nt][r] = p;
                    sum += p;
                }
            sum += __shfl_xor(sum, 16);
            sum += __shfl_xor(sum, 32);
            inv[nt] = 1.0f / sum;
        }

        // ---- P -> bf16 B-fragments (in-lane; layout matches 16x16x16 B) ----
        bf16x4 pb[4][4];
        #pragma unroll
        for (int mt = 0; mt < 4; ++mt)
            #pragma unroll
            for (int nt = 0; nt < 4; ++nt) {
                u32 pk[2];
                pk[0] = cvtpk(s[mt][nt][0], s[mt][nt][1]);
                pk[1] = cvtpk(s[mt][nt][2], s[mt][nt][3]);
                bf16x4 bv;
                __builtin_memcpy(&bv, pk, 8);
                pb[mt][nt] = bv;
            }

        // ---- PV: out^T[d,q] = V^T @ P^T via 16x16x16 MFMA ----
        f32x4 o[2][4];
        #pragma unroll
        for (int ma = 0; ma < 2; ++ma)
            #pragma unroll
            for (int nt = 0; nt < 4; ++nt) o[ma][nt] = (f32x4){0.f, 0.f, 0.f, 0.f};
        #pragma unroll
        for (int kt = 0; kt < 4; ++kt) {
            bf16x4 a0 = *(const bf16x4*)&Vt[h][q15][16 * kt + 4 * g];
            bf16x4 a1 = *(const bf16x4*)&Vt[h][16 + q15][16 * kt + 4 * g];
            #pragma unroll
            for (int nt = 0; nt < 4; ++nt) {
                o[0][nt] = mfma16(a0, pb[kt][nt], o[0][nt]);
                o[1][nt] = mfma16(a1, pb[kt][nt], o[1][nt]);
            }
        }

        // ---- scale by 1/l, pack, store (8B per store, 4 consecutive ch) ----
        u16* ob = outb + (size_t)(w * 64) * 256 + h * 32;
        #pragma unroll
        for (int nt = 0; nt < 4; ++nt) {
            float iv = inv[nt];
            int tok = 16 * nt + q15;
            #pragma unroll
            for (int ma = 0; ma < 2; ++ma) {
                uint2 val;
                val.x = cvtpk(o[ma][nt][0] * iv, o[ma][nt][1] * iv);
                val.y = cvtpk(o[ma][nt][2] * iv, o[ma][nt][3] * iv);
                *(uint2*)(ob + (size_t)tok * 256 + 16 * ma + 4 * g) = val;
            }
        }
    }
}

extern "C" void kernel_launch(void* const* d_in, const int* in_sizes, int n_in,
                              void* d_out, int out_size, void* d_ws, size_t ws_size,
                              hipStream_t stream) {
    const float* x     = (const float*)d_in[0];
    const float* mask  = (const float*)d_in[1];
    const float* n1w   = (const float*)d_in[2];
    const float* n1b   = (const float*)d_in[3];
    const float* qkvw  = (const float*)d_in[4];
    const float* qkvbi = (const float*)d_in[5];
    const float* posw  = (const float*)d_in[6];
    const float* posb  = (const float*)d_in[7];
    const float* projw = (const float*)d_in[8];
    const float* projb = (const float*)d_in[9];
    const float* n2w   = (const float*)d_in[10];
    const float* n2b   = (const float*)d_in[11];
    const float* fc1w  = (const float*)d_in[12];
    const float* fc1b  = (const float*)d_in[13];
    const float* fc2w  = (const float*)d_in[14];
    const float* fc2b  = (const float*)d_in[15];

    // per-chunk scratch, TC tokens (CB whole batches so roll stays chunk-local):
    //   hs/h2 : [0,        TC*512)   bf16 TCx256
    //   attn  : [TC*512,   TC*1024)  bf16 TCx256
    //   x1    : [TC*1024,  TC*2048)  fp32 TCx256
    //   qkv   : [TC*2048,  TC*3584)  bf16 TCx768
    //   mid   : aliases [TC*2048, TC*4096) bf16 TCx1024 (qkv dead by then)
    //   wbf   : [TC*4096, +1966096)  bf16 weights (incl. zero16)
    //   bias2 : [+1966096, +1967120) fp32 256
    int CB = 32;
    while (CB > 1 && (size_t)CB * 4096 * 4096 + 1967120ull > ws_size) CB >>= 1;
    const int TC = CB * 4096;

    char* ws = (char*)d_ws;
    u16*   hs   = (u16*)ws;
    u16*   attn = (u16*)(ws + (size_t)TC * 512);
    float* x1   = (float*)(ws + (size_t)TC * 1024);
    u16*   qkv  = (u16*)(ws + (size_t)TC * 2048);
    u16*   mid  = qkv;
    u16*   wbf  = (u16*)(ws + (size_t)TC * 4096);
    u16* qkvw_b = wbf;
    u16* fc1w_b = wbf + 196608;
    u16* fc2w_b = wbf + 458752;
    u16* pjl    = wbf + 720896;
    u16* zero16 = wbf + 983040;
    float* bias2 = (float*)((char*)wbf + 1966096);

    cvt_kernel<<<3841, 256, 0, stream>>>(qkvw, projw, fc1w, fc2w, wbf);
    compose_kernel<<<256, 256, 0, stream>>>(projw, posw, projb, posb, pjl, bias2);

    for (int t0 = 0; t0 < TT; t0 += TC) {
        const float* xc = x + (size_t)t0 * 256;
        // 1. LN1 + roll(-32)   (t0 multiple of 4096 -> roll chunk-local)
        ln_kernel<32><<<TC / 4, 256, 0, stream>>>(xc, n1w, n1b, hs);
        // 2. QKV GEMM (bf16 MFMA)
        mgemm<0, 0, 0><<<dim3(TC / 256, 6), 256, 0, stream>>>(
            hs, nullptr, qkvw_b, nullptr, qkvbi, qkv, nullptr, nullptr, 768, 256);
        // 3. windowed attention (MFMA, one block per window)
        attn_mfma<<<TC / 64, 256, 0, stream>>>(qkv, mask, attn);
        // 4. fused (attn@proj^T + v_taps@(proj·posw)^T) + reverse-roll + residual -> x1
        mgemm<2, 0, 1><<<dim3(TC / 256, 2), 256, 0, stream>>>(
            attn, qkv, pjl, zero16, bias2, nullptr, x1, xc, 256, 1024);
        // 5. LN2
        ln_kernel<0><<<TC / 4, 256, 0, stream>>>(x1, n2w, n2b, hs);
        // 6. FC1 + exact GELU
        mgemm<0, 1, 0><<<dim3(TC / 256, 8), 256, 0, stream>>>(
            hs, nullptr, fc1w_b, nullptr, fc1b, mid, nullptr, nullptr, 1024, 256);
        // 7. FC2 + residual -> d_out (fp32)
        mgemm<3, 0, 0><<<dim3(TC / 256, 2), 256, 0, stream>>>(
            mid, nullptr, fc2w_b, nullptr, fc2b, nullptr,
            (float*)d_out + (size_t)t0 * 256, x1, 256, 1024);
    }
}

// Round 5
// 1026.341 us; speedup vs baseline: 1.3930x; 1.3930x over previous
//
#include <hip/hip_runtime.h>

typedef unsigned short u16;
typedef unsigned int   u32;
typedef short bf16x8 __attribute__((ext_vector_type(8)));
typedef short bf16x4 __attribute__((ext_vector_type(4)));
typedef float f32x4  __attribute__((ext_vector_type(4)));

#define TT   131072         // B*N tokens
#define SCALE 0.17677669529663687f

__device__ __forceinline__ float bf2f(u32 u) {
    u32 v = u << 16;
    float f;
    __builtin_memcpy(&f, &v, 4);
    return f;
}
__device__ __forceinline__ u16 f2bf(float f) {
    u32 v;
    __builtin_memcpy(&v, &f, 4);
    u32 r = v + 0x7fffu + ((v >> 16) & 1u);
    return (u16)(r >> 16);
}

// pack two f32 -> one u32 of 2 bf16 (RNE) in a single instruction
__device__ __forceinline__ u32 cvtpk(float a, float b) {
    u32 r;
    asm("v_cvt_pk_bf16_f32 %0, %1, %2" : "=v"(r) : "v"(a), "v"(b));
    return r;
}

#if __has_builtin(__builtin_amdgcn_mfma_f32_16x16x16bf16_1k)
#define HAVE_MFMA16_BUILTIN 1
#endif

__device__ __forceinline__ f32x4 mfma16(bf16x4 a, bf16x4 b, f32x4 c) {
#ifdef HAVE_MFMA16_BUILTIN
    return __builtin_amdgcn_mfma_f32_16x16x16bf16_1k(a, b, c, 0, 0, 0);
#else
    asm volatile("v_mfma_f32_16x16x16_bf16 %0, %1, %2, %0"
                 : "+v"(c) : "v"(a), "v"(b));
    return c;
#endif
}

// async global->LDS, 16B per lane, dest = uniform base + lane*16
#define GLD16(g, l)                                                           \
    __builtin_amdgcn_global_load_lds(                                         \
        (const __attribute__((address_space(1))) void*)(g),                   \
        (__attribute__((address_space(3))) void*)(l), 16, 0, 0)

// ---------------- weight fp32 -> bf16 conversion (once per launch) ----------
// wbf element layout:
//   qkvw [0,196608)  fc1w [196608,458752)  fc2w [458752,720896)
//   pjl  [720896,983040)  rows c of [projw(256) | W'(768)]  (W' by compose)
//   zero16 [983040,983048)
__global__ __launch_bounds__(256) void cvt_kernel(
    const float* __restrict__ qkvw, const float* __restrict__ projw,
    const float* __restrict__ fc1w, const float* __restrict__ fc2w,
    u16* __restrict__ dst) {
    int i = blockIdx.x * 256 + threadIdx.x;
    if (i >= 983048) return;
    float v;
    if (i < 196608)       v = qkvw[i];
    else if (i < 458752)  v = fc1w[i - 196608];
    else if (i < 720896)  v = fc2w[i - 458752];
    else if (i < 983040) {
        int local = i - 720896;
        int kk = local & 1023;
        if (kk >= 256) return;          // W' part written by compose_kernel
        v = projw[(local >> 10) * 256 + kk];
    } else v = 0.0f;                    // zero16 block
    dst[i] = f2bf(v);
}

// ---- compose W'[c, tap*256+ci] = sum_j projw[c,j]*posw[j,ci,tap] (fp32) ----
// also bias2[c] = projb[c] + sum_j projw[c,j]*posb[j]
__global__ __launch_bounds__(256) void compose_kernel(
    const float* __restrict__ projw, const float* __restrict__ posw,
    const float* __restrict__ projb, const float* __restrict__ posb,
    u16* __restrict__ pjl, float* __restrict__ bias2) {
    int c = blockIdx.x, t = threadIdx.x;
    __shared__ float pr[256];
    pr[t] = projw[c * 256 + t];
    __syncthreads();
    #pragma unroll
    for (int r = 0; r < 3; ++r) {
        int kp = r * 256 + t;
        int tap = kp >> 8, ci = kp & 255;
        float acc = 0.f;
        for (int j = 0; j < 256; ++j)
            acc += pr[j] * posw[j * 768 + ci * 3 + tap];
        pjl[(size_t)c * 1024 + 256 + kp] = f2bf(acc);
    }
    float b = pr[t] * posb[t];
    #pragma unroll
    for (int o = 32; o > 0; o >>= 1) b += __shfl_down(b, o);
    __shared__ float pb4[4];
    if ((t & 63) == 0) pb4[t >> 6] = b;
    __syncthreads();
    if (t == 0) bias2[c] = projb[c] + pb4[0] + pb4[1] + pb4[2] + pb4[3];
}

// ---------------- LayerNorm (+optional intra-batch roll), fp32 in -> bf16 out
// wave-per-token: 4 tokens/block, 64 lanes x 4ch, shuffle-only reduction.
template <int SH>
__global__ __launch_bounds__(256) void ln_kernel(const float* __restrict__ x,
                                                 const float* __restrict__ w,
                                                 const float* __restrict__ bb,
                                                 u16* __restrict__ out) {
    int wid = threadIdx.x >> 6, lane = threadIdx.x & 63;
    int tl = blockIdx.x * 4 + wid;
    int src = (tl & ~4095) | ((tl + SH) & 4095);
    int c = lane * 4;
    float4 v = *(const float4*)(x + (size_t)src * 256 + c);
    float s1 = v.x + v.y + v.z + v.w;
    float s2 = v.x * v.x + v.y * v.y + v.z * v.z + v.w * v.w;
    #pragma unroll
    for (int o = 32; o > 0; o >>= 1) {
        s1 += __shfl_xor(s1, o);
        s2 += __shfl_xor(s2, o);
    }
    float mean = s1 * (1.0f / 256.0f);
    float rs = rsqrtf(s2 * (1.0f / 256.0f) - mean * mean + 1e-5f);
    float4 wv = *(const float4*)(w + c);
    float4 bv = *(const float4*)(bb + c);
    uint2 o2;
    o2.x = cvtpk((v.x - mean) * rs * wv.x + bv.x, (v.y - mean) * rs * wv.y + bv.y);
    o2.y = cvtpk((v.z - mean) * rs * wv.z + bv.z, (v.w - mean) * rs * wv.w + bv.w);
    *(uint2*)(out + (size_t)tl * 256 + c) = o2;
}

// ---------------- MFMA GEMM: C = A[M,K]bf16 @ W[Nc,K]bf16^T + bias ----------
// 128x128 tile, BK=32, 4 waves (2x2 of 64x64), 16x16x32 bf16 MFMA, fp32 acc.
// Double-buffered LDS with COUNTED vmcnt (m201/T4 recipe): prefetch issued at
// top of iter; s_waitcnt vmcnt(4) waits only the CURRENT buffer's 4 loads
// (oldest; VM counter decrements in issue order) while the 4 prefetch loads
// stay in flight across BOTH raw s_barriers. lgkmcnt(0)+barrier after compute
// protects the buffer from next iter's overwrite. No vmcnt(0) in main loop.
// MODE 0: Cb[r*Nc+c]  = v                         (qkv / fc1)
// MODE 2: Cf[drl*256+c] = v + resf[drl*256+c]     (proj + reverse-roll + residual)
// MODE 3: Cf[r*256+c]   = v + resf[r*256+c]       (fc2 + residual -> d_out)
// ACT 1: exact GELU
// AM 1: fused proj+LePE A-operand: K=1024, row t = [attn(256) | v(t-1) | v(t) | v(t+1)]
//       attn from A, v-taps direct from qkv (A2); window-edge taps -> Z (zeros)
template <int MODE, int ACT, int AM>
__global__ __launch_bounds__(256) void mgemm(
    const u16* __restrict__ A, const u16* __restrict__ A2,
    const u16* __restrict__ W, const u16* __restrict__ Z,
    const float* __restrict__ bias, u16* __restrict__ Cb,
    float* __restrict__ Cf, const float* __restrict__ resf,
    int Nc, int K) {
    __shared__ u16 As[2][128 * 32];
    __shared__ u16 Bs[2][128 * 32];
    const int tid = threadIdx.x;
    const int m0 = blockIdx.x * 128, n0 = blockIdx.y * 128;
    const int w4 = tid >> 6, lane = tid & 63;
    // staging: wave w covers rows 32w..32w+31 of the tile; lane -> (row, 16B group)
    const int srow = 32 * w4 + (lane >> 2);
    const int scol = (lane & 3) * 8;                 // element offset in row
    const u16* ag = (AM == 0) ? A + (size_t)(m0 + srow) * K + scol : A;
    const u16* bg = W + (size_t)(n0 + srow) * K + scol;
    const int lofs = w4 * 1024;                      // 32 rows * 32 elem
    // fragments
    const int frow = lane & 15, fk = (lane >> 4) * 8;
    const int am = (w4 & 1) * 64, bn = (w4 >> 1) * 64;

    // AM==1: precomputed per-region A bases for rows t0=m0+srow, t1=t0+16
    const u16 *pA00, *pA10, *pA01, *pA11, *pA02, *pA12, *pA03, *pA13;
    u32 m0r1 = ~0u, m1r1 = ~0u, m0r3 = ~0u, m1r3 = ~0u;
    if constexpr (AM == 1) {
        int t0 = m0 + srow, t1 = t0 + 16;
        int tq0 = t0 & 63, tq1 = t1 & 63;
        pA00 = A + (size_t)t0 * 256 + scol;
        pA10 = A + (size_t)t1 * 256 + scol;
        pA01 = (tq0 > 0)  ? A2 + (long)(t0 - 1) * 768 + 512 + scol : Z;
        m0r1 = (tq0 > 0)  ? ~0u : 0u;
        pA11 = (tq1 > 0)  ? A2 + (long)(t1 - 1) * 768 + 512 + scol : Z;
        m1r1 = (tq1 > 0)  ? ~0u : 0u;
        pA02 = A2 + (size_t)t0 * 768 + 512 + scol;
        pA12 = A2 + (size_t)t1 * 768 + 512 + scol;
        pA03 = (tq0 < 63) ? A2 + (long)(t0 + 1) * 768 + 512 + scol : Z;
        m0r3 = (tq0 < 63) ? ~0u : 0u;
        pA13 = (tq1 < 63) ? A2 + (long)(t1 + 1) * 768 + 512 + scol : Z;
        m1r3 = (tq1 < 63) ? ~0u : 0u;
    }

    f32x4 acc[4][4];
    #pragma unroll
    for (int i = 0; i < 4; ++i)
        #pragma unroll
        for (int j = 0; j < 4; ++j) acc[i][j] = (f32x4){0.f, 0.f, 0.f, 0.f};

    auto STAGE = [&](int b, int k0) {
        u16* lA = &As[b][lofs];
        u16* lB = &Bs[b][lofs];
        if constexpr (AM == 1) {
            int kl = k0 & 255;
            const u16 *p0, *p1;
            u32 q0 = ~0u, q1 = ~0u;
            switch (k0 >> 8) {
                case 0:  p0 = pA00; p1 = pA10; break;
                case 1:  p0 = pA01; p1 = pA11; q0 = m0r1; q1 = m1r1; break;
                case 2:  p0 = pA02; p1 = pA12; break;
                default: p0 = pA03; p1 = pA13; q0 = m0r3; q1 = m1r3; break;
            }
            GLD16(p0 + (kl & q0), lA);
            GLD16(p1 + (kl & q1), lA + 512);
        } else {
            GLD16(ag + k0, lA);
            GLD16(ag + k0 + (size_t)16 * K, lA + 512);
        }
        GLD16(bg + k0, lB);
        GLD16(bg + (size_t)16 * K + k0, lB + 512);
    };
    auto COMPUTE = [&](int b) {
        bf16x8 af[4], bfr[4];
        #pragma unroll
        for (int mi = 0; mi < 4; ++mi)
            af[mi] = *(const bf16x8*)&As[b][(am + mi * 16 + frow) * 32 + fk];
        #pragma unroll
        for (int ni = 0; ni < 4; ++ni)
            bfr[ni] = *(const bf16x8*)&Bs[b][(bn + ni * 16 + frow) * 32 + fk];
        #pragma unroll
        for (int mi = 0; mi < 4; ++mi)
            #pragma unroll
            for (int ni = 0; ni < 4; ++ni)
                acc[mi][ni] = __builtin_amdgcn_mfma_f32_16x16x32_bf16(
                    af[mi], bfr[ni], acc[mi][ni], 0, 0, 0);
    };

    // prologue: stage buffer 0
    STAGE(0, 0);
    int cur = 0;
    const int nt = K >> 5;
    for (int t = 0; t < nt - 1; ++t) {
        STAGE(cur ^ 1, (t + 1) << 5);   // prefetch next (stays in flight
                                        //  across both barriers below)
        // oldest 4 outstanding loads == buffer `cur`; wait only those
        asm volatile("s_waitcnt vmcnt(4)" ::: "memory");
        __builtin_amdgcn_s_barrier();   // all waves: cur fully staged
        COMPUTE(cur);
        asm volatile("s_waitcnt lgkmcnt(0)" ::: "memory");
        __builtin_amdgcn_s_barrier();   // all waves done reading cur ->
        cur ^= 1;                       //  safe to overwrite next iter
    }
    asm volatile("s_waitcnt vmcnt(0)" ::: "memory");
    __builtin_amdgcn_s_barrier();
    COMPUTE(cur);                       // last tile (no prefetch)

    // epilogue; C/D layout: col = lane&15, row = (lane>>4)*4 + reg
    const int erow = am + ((lane >> 4) << 2);
    const int ecol = bn + (lane & 15);
    #pragma unroll
    for (int ni = 0; ni < 4; ++ni) {
        int c = n0 + ecol + ni * 16;
        float bv = bias[c];
        #pragma unroll
        for (int mi = 0; mi < 4; ++mi) {
            #pragma unroll
            for (int reg = 0; reg < 4; ++reg) {
                int r = m0 + erow + mi * 16 + reg;
                float v = acc[mi][ni][reg] + bv;
                if (ACT == 1) v = 0.5f * v * (1.0f + erff(v * 0.70710678118654752f));
                if (MODE == 0) {
                    Cb[(size_t)r * Nc + c] = f2bf(v);
                } else if (MODE == 2) {
                    size_t drl = (size_t)((r & ~4095) | ((r + 32) & 4095));
                    Cf[drl * 256 + c] = v + resf[drl * 256 + c];
                } else {
                    Cf[(size_t)r * 256 + c] = v + resf[(size_t)r * 256 + c];
                }
            }
        }
    }
}

// ---------------- MFMA attention: one block per window, wave = 2 heads ------
// Swapped QK^T: S^T[k,q] = mfma_16x16x32(K-rows, Q-rows). Lane (g=lane>>4,
// q15=lane&15) holds S^T[16*mt+4*g+r, 16*nt+q15] — which is EXACTLY the
// B-fragment layout of v_mfma_f32_16x16x16_bf16 (lane holds B[4g+j, q15],
// j == reg). So softmax + cvt_pk happen fully in-lane, then PV computes
// out^T = V^T @ P^T with V^T staged in LDS (32x[64+pad] per head).
__global__ __launch_bounds__(256) void attn_mfma(const u16* __restrict__ qkv,
                                                 const float* __restrict__ mask,
                                                 u16* __restrict__ outb) {
    __shared__ u16 Vt[8][32][68];     // V^T per head, k-pad 68 (8B-aligned rows)
    __shared__ float Mt[64][68];      // mask^T [k][q], pad 68 -> 2-way reads
    __shared__ int mflag;

    const int w   = blockIdx.x;       // global window within chunk
    const int nw  = w & 63;           // window within batch
    const int tid = threadIdx.x;
    const int wid = tid >> 6, lane = tid & 63;
    const int g = lane >> 4, q15 = lane & 15;

    if (tid == 0) mflag = 0;
    __syncthreads();

    // ---- stage mask^T + nonzero detect (all-zero for most windows) ----
    {
        const float* mrow = mask + (size_t)nw * 4096;
        int nz = 0;
        #pragma unroll
        for (int i = 0; i < 16; ++i) {
            int e = i * 256 + tid;                  // e = q*64 + k
            float m = mrow[e];
            nz |= (m != 0.0f);
            Mt[e & 63][e >> 6] = m;
        }
        if (nz) mflag = 1;
    }

    // ---- stage V^T for all 8 heads (write banks: lanes walk t -> free) ----
    {
        const u16* vg = qkv + (size_t)(w * 64) * 768 + 512;
        #pragma unroll
        for (int p = 0; p < 8; ++p) {
            int t  = lane;                          // token within window
            int c0 = wid * 8 + p * 32;              // channel base (uniform/wave)
            uint4 u = *(const uint4*)(vg + (size_t)t * 768 + c0);
            u16 el[8];
            *(uint4*)el = u;
            int h = c0 >> 5, d0 = c0 & 31;
            #pragma unroll
            for (int j = 0; j < 8; ++j) Vt[h][d0 + j][t] = el[j];
        }
    }
    __syncthreads();

    const int hasmask = mflag;

    #pragma unroll
    for (int hh = 0; hh < 2; ++hh) {
        const int h = wid * 2 + hh;

        // ---- QK^T (swapped): A = K rows, B = Q rows, direct from global ----
        const u16* kbase = qkv + (size_t)(w * 64) * 768 + 256 + h * 32 + g * 8;
        const u16* qbase = qkv + (size_t)(w * 64) * 768 +       h * 32 + g * 8;
        bf16x8 kf[4], qf[4];
        #pragma unroll
        for (int mt = 0; mt < 4; ++mt)
            kf[mt] = *(const bf16x8*)(kbase + (size_t)(16 * mt + q15) * 768);
        #pragma unroll
        for (int nt = 0; nt < 4; ++nt)
            qf[nt] = *(const bf16x8*)(qbase + (size_t)(16 * nt + q15) * 768);

        f32x4 s[4][4];
        #pragma unroll
        for (int mt = 0; mt < 4; ++mt)
            #pragma unroll
            for (int nt = 0; nt < 4; ++nt) s[mt][nt] = (f32x4){0.f, 0.f, 0.f, 0.f};
        #pragma unroll
        for (int mt = 0; mt < 4; ++mt)
            #pragma unroll
            for (int nt = 0; nt < 4; ++nt)
                s[mt][nt] = __builtin_amdgcn_mfma_f32_16x16x32_bf16(
                    kf[mt], qf[nt], s[mt][nt], 0, 0, 0);

        // ---- scale (+mask) ----
        if (hasmask) {
            #pragma unroll
            for (int mt = 0; mt < 4; ++mt)
                #pragma unroll
                for (int nt = 0; nt < 4; ++nt)
                    #pragma unroll
                    for (int r = 0; r < 4; ++r)
                        s[mt][nt][r] = s[mt][nt][r] * SCALE +
                                       Mt[16 * mt + 4 * g + r][16 * nt + q15];
        } else {
            #pragma unroll
            for (int mt = 0; mt < 4; ++mt)
                #pragma unroll
                for (int nt = 0; nt < 4; ++nt)
                    #pragma unroll
                    for (int r = 0; r < 4; ++r)
                        s[mt][nt][r] *= SCALE;
        }

        // ---- softmax over k (rows of S^T): in-lane 16 + shfl_xor 16/32 ----
        float inv[4];
        #pragma unroll
        for (int nt = 0; nt < 4; ++nt) {
            float mx = -3.0e38f;
            #pragma unroll
            for (int mt = 0; mt < 4; ++mt)
                #pragma unroll
                for (int r = 0; r < 4; ++r) mx = fmaxf(mx, s[mt][nt][r]);
            mx = fmaxf(mx, __shfl_xor(mx, 16));
            mx = fmaxf(mx, __shfl_xor(mx, 32));
            float sum = 0.f;
            #pragma unroll
            for (int mt = 0; mt < 4; ++mt)
                #pragma unroll
                for (int r = 0; r < 4; ++r) {
                    float p = __expf(s[mt][nt][r] - mx);
                    s[mt][nt][r] = p;
                    sum += p;
                }
            sum += __shfl_xor(sum, 16);
            sum += __shfl_xor(sum, 32);
            inv[nt] = 1.0f / sum;
        }

        // ---- P -> bf16 B-fragments (in-lane; layout matches 16x16x16 B) ----
        bf16x4 pb[4][4];
        #pragma unroll
        for (int mt = 0; mt < 4; ++mt)
            #pragma unroll
            for (int nt = 0; nt < 4; ++nt) {
                u32 pk[2];
                pk[0] = cvtpk(s[mt][nt][0], s[mt][nt][1]);
                pk[1] = cvtpk(s[mt][nt][2], s[mt][nt][3]);
                bf16x4 bv;
                __builtin_memcpy(&bv, pk, 8);
                pb[mt][nt] = bv;
            }

        // ---- PV: out^T[d,q] = V^T @ P^T via 16x16x16 MFMA ----
        f32x4 o[2][4];
        #pragma unroll
        for (int ma = 0; ma < 2; ++ma)
            #pragma unroll
            for (int nt = 0; nt < 4; ++nt) o[ma][nt] = (f32x4){0.f, 0.f, 0.f, 0.f};
        #pragma unroll
        for (int kt = 0; kt < 4; ++kt) {
            bf16x4 a0 = *(const bf16x4*)&Vt[h][q15][16 * kt + 4 * g];
            bf16x4 a1 = *(const bf16x4*)&Vt[h][16 + q15][16 * kt + 4 * g];
            #pragma unroll
            for (int nt = 0; nt < 4; ++nt) {
                o[0][nt] = mfma16(a0, pb[kt][nt], o[0][nt]);
                o[1][nt] = mfma16(a1, pb[kt][nt], o[1][nt]);
            }
        }

        // ---- scale by 1/l, pack, store (8B per store, 4 consecutive ch) ----
        u16* ob = outb + (size_t)(w * 64) * 256 + h * 32;
        #pragma unroll
        for (int nt = 0; nt < 4; ++nt) {
            float iv = inv[nt];
            int tok = 16 * nt + q15;
            #pragma unroll
            for (int ma = 0; ma < 2; ++ma) {
                uint2 val;
                val.x = cvtpk(o[ma][nt][0] * iv, o[ma][nt][1] * iv);
                val.y = cvtpk(o[ma][nt][2] * iv, o[ma][nt][3] * iv);
                *(uint2*)(ob + (size_t)tok * 256 + 16 * ma + 4 * g) = val;
            }
        }
    }
}

extern "C" void kernel_launch(void* const* d_in, const int* in_sizes, int n_in,
                              void* d_out, int out_size, void* d_ws, size_t ws_size,
                              hipStream_t stream) {
    const float* x     = (const float*)d_in[0];
    const float* mask  = (const float*)d_in[1];
    const float* n1w   = (const float*)d_in[2];
    const float* n1b   = (const float*)d_in[3];
    const float* qkvw  = (const float*)d_in[4];
    const float* qkvbi = (const float*)d_in[5];
    const float* posw  = (const float*)d_in[6];
    const float* posb  = (const float*)d_in[7];
    const float* projw = (const float*)d_in[8];
    const float* projb = (const float*)d_in[9];
    const float* n2w   = (const float*)d_in[10];
    const float* n2b   = (const float*)d_in[11];
    const float* fc1w  = (const float*)d_in[12];
    const float* fc1b  = (const float*)d_in[13];
    const float* fc2w  = (const float*)d_in[14];
    const float* fc2b  = (const float*)d_in[15];

    // per-chunk scratch, TC tokens (CB whole batches so roll stays chunk-local):
    //   hs/h2 : [0,        TC*512)   bf16 TCx256
    //   attn  : [TC*512,   TC*1024)  bf16 TCx256
    //   x1    : [TC*1024,  TC*2048)  fp32 TCx256
    //   qkv   : [TC*2048,  TC*3584)  bf16 TCx768
    //   mid   : aliases [TC*2048, TC*4096) bf16 TCx1024 (qkv dead by then)
    //   wbf   : [TC*4096, +1966096)  bf16 weights (incl. zero16)
    //   bias2 : [+1966096, +1967120) fp32 256
    int CB = 32;
    while (CB > 1 && (size_t)CB * 4096 * 4096 + 1967120ull > ws_size) CB >>= 1;
    const int TC = CB * 4096;

    char* ws = (char*)d_ws;
    u16*   hs   = (u16*)ws;
    u16*   attn = (u16*)(ws + (size_t)TC * 512);
    float* x1   = (float*)(ws + (size_t)TC * 1024);
    u16*   qkv  = (u16*)(ws + (size_t)TC * 2048);
    u16*   mid  = qkv;
    u16*   wbf  = (u16*)(ws + (size_t)TC * 4096);
    u16* qkvw_b = wbf;
    u16* fc1w_b = wbf + 196608;
    u16* fc2w_b = wbf + 458752;
    u16* pjl    = wbf + 720896;
    u16* zero16 = wbf + 983040;
    float* bias2 = (float*)((char*)wbf + 1966096);

    cvt_kernel<<<3841, 256, 0, stream>>>(qkvw, projw, fc1w, fc2w, wbf);
    compose_kernel<<<256, 256, 0, stream>>>(projw, posw, projb, posb, pjl, bias2);

    for (int t0 = 0; t0 < TT; t0 += TC) {
        const float* xc = x + (size_t)t0 * 256;
        // 1. LN1 + roll(-32)   (t0 multiple of 4096 -> roll chunk-local)
        ln_kernel<32><<<TC / 4, 256, 0, stream>>>(xc, n1w, n1b, hs);
        // 2. QKV GEMM (bf16 MFMA)
        mgemm<0, 0, 0><<<dim3(TC / 128, 6), 256, 0, stream>>>(
            hs, nullptr, qkvw_b, nullptr, qkvbi, qkv, nullptr, nullptr, 768, 256);
        // 3. windowed attention (MFMA, one block per window)
        attn_mfma<<<TC / 64, 256, 0, stream>>>(qkv, mask, attn);
        // 4. fused (attn@proj^T + v_taps@(proj·posw)^T) + reverse-roll + residual -> x1
        mgemm<2, 0, 1><<<dim3(TC / 128, 2), 256, 0, stream>>>(
            attn, qkv, pjl, zero16, bias2, nullptr, x1, xc, 256, 1024);
        // 5. LN2
        ln_kernel<0><<<TC / 4, 256, 0, stream>>>(x1, n2w, n2b, hs);
        // 6. FC1 + exact GELU
        mgemm<0, 1, 0><<<dim3(TC / 128, 8), 256, 0, stream>>>(
            hs, nullptr, fc1w_b, nullptr, fc1b, mid, nullptr, nullptr, 1024, 256);
        // 7. FC2 + residual -> d_out (fp32)
        mgemm<3, 0, 0><<<dim3(TC / 128, 2), 256, 0, stream>>>(
            mid, nullptr, fc2w_b, nullptr, fc2b, nullptr,
            (float*)d_out + (size_t)t0 * 256, x1, 256, 1024);
    }
}